// Round 2
// baseline (297.625 us; speedup 1.0000x reference)
//
#include <hip/hip_runtime.h>

// StripPooling (fp32): x (8,64,256,256); PS=16.
// ws layout (floats): hp[8192] @0, vp[8192] @8192, fh[8192] @16384, fv[8192] @24576.
// hp/vp/fh/fv logical shape (B*C, 16) row-major.

#define B_ 8
#define C_ 64
#define H_ 256
#define W_ 256
#define EPS_ 1e-5f

// ---------------- Kernel 1: strip pooling ----------------
// grid 512 (one block per (b,c) plane), block 256.
// thread t: tw = t&63 -> w chunk [4*tw, 4*tw+4); th = t>>6 (== wave) -> h offset.
__global__ void __launch_bounds__(256) k_pool(const float* __restrict__ x,
                                              float* __restrict__ ws) {
    const int bc = blockIdx.x;
    const int t  = threadIdx.x;
    const int tw = t & 63;
    const int th = t >> 6;            // 0..3, equals wave index
    const float4* xv = (const float4*)(x + (size_t)bc * (H_ * W_));

    float hbin[16];
#pragma unroll
    for (int p = 0; p < 16; ++p) hbin[p] = 0.f;
    float colsum = 0.f;

#pragma unroll
    for (int hi = 0; hi < 64; ++hi) {
        const int h = hi * 4 + th;            // covers all 256 rows
        float4 v = xv[h * 64 + tw];           // 4 floats, coalesced 1KB/wave
        float s = v.x + v.y + v.z + v.w;
        hbin[hi >> 2] += s;                   // h>>4 == hi>>2 since th<4
        colsum += s;
    }

    __shared__ float hpr[4][16];
    __shared__ float vpr[4][16];
    const int wave = t >> 6, lane = t & 63;

#pragma unroll
    for (int p = 0; p < 16; ++p) {
        float v = hbin[p];
        for (int off = 32; off; off >>= 1) v += __shfl_down(v, off);
        if (lane == 0) hpr[wave][p] = v;
    }
    // w-bin = (4*tw)>>4 = tw>>2 : groups of 4 lanes share one bin
    float vsum = colsum + __shfl_down(colsum, 2, 4);
    vsum += __shfl_down(vsum, 1, 4);
    if ((lane & 3) == 0) vpr[wave][lane >> 2] = vsum;
    __syncthreads();

    if (t < 16) {
        float hv = hpr[0][t] + hpr[1][t] + hpr[2][t] + hpr[3][t];
        ws[bc * 16 + t] = hv * (1.f / 4096.f);          // mean over 16*256
        float vv = vpr[0][t] + vpr[1][t] + vpr[2][t] + vpr[3][t];
        ws[8192 + bc * 16 + t] = vv * (1.f / 4096.f);   // mean over 256*16
    }
}

// ---------------- Kernel 2: conv+BN chains on pooled strips ----------------
// grid 16: blockIdx>>3 = path (0:h,1:v), blockIdx&7 = b. block 256.
__global__ void __launch_bounds__(256) k_mix(
    const float* __restrict__ Wh, const float* __restrict__ bh,
    const float* __restrict__ Wv, const float* __restrict__ bv,
    const float* __restrict__ Wf, const float* __restrict__ bfv,
    const float* __restrict__ gh, const float* __restrict__ beh,
    const float* __restrict__ muh, const float* __restrict__ vah,
    const float* __restrict__ gv, const float* __restrict__ bev,
    const float* __restrict__ muv, const float* __restrict__ vav,
    float* __restrict__ ws) {
    const int path = blockIdx.x >> 3;
    const int b    = blockIdx.x & 7;
    const float* P = ws + path * 8192 + b * 1024;          // pooled (64 x 16)
    float* Z       = ws + 16384 + path * 8192 + b * 1024;  // fh / fv out
    const float* W1 = path ? Wv : Wh;
    const float* b1 = path ? bv : bh;
    const float* gg = path ? gv : gh;
    const float* bb = path ? bev : beh;
    const float* mm = path ? muv : muh;
    const float* vv = path ? vav : vah;

    __shared__ float Pl[1024];
    __shared__ float Yl[1024];
    __shared__ float W1l[4096];
    __shared__ float W2l[4096];
    const int t = threadIdx.x;
    for (int i = t; i < 1024; i += 256) Pl[i] = P[i];
    for (int i = t; i < 4096; i += 256) {
        W1l[i] = W1[i];
        const int o = i >> 6, c = i & 63;
        W2l[i] = Wf[o * 128 + path * 64 + c];   // Wf[:, :C] or Wf[:, C:]
    }
    __syncthreads();

    // Stage A: Y = BN(W1 @ P + b1)   (Y stored as [c][p], c=out-channel, p=strip)
#pragma unroll
    for (int r = 0; r < 4; ++r) {
        const int j = t + 256 * r;
        const int c = j >> 4, p = j & 15;
        float acc = 0.f;
#pragma unroll
        for (int k = 0; k < 64; ++k) acc += W1l[c * 64 + k] * Pl[k * 16 + p];
        const float inv = gg[c] * rsqrtf(vv[c] + EPS_);
        Yl[j] = inv * (acc + b1[c]) + bb[c] - mm[c] * inv;
    }
    __syncthreads();

    // Stage B: Z = Wf_half @ Y (+ bf on the v path only)
#pragma unroll
    for (int r = 0; r < 4; ++r) {
        const int j = t + 256 * r;
        const int o = j >> 4, p = j & 15;
        float acc = path ? bfv[o] : 0.f;
#pragma unroll
        for (int k = 0; k < 64; ++k) acc += W2l[o * 64 + k] * Yl[k * 16 + p];
        Z[j] = acc;
    }
}

// ---------------- Kernel 3: epilogue ----------------
// out = sigmoid(BN_f(fh + fv)) * x. One thread per 4-elt w-chunk (4-aligned
// chunks never cross a 16-wide w-bin -> one sigmoid per thread).
// grid 32768, block 256.
__global__ void __launch_bounds__(256) k_out(
    const float* __restrict__ x,
    const float* __restrict__ gf, const float* __restrict__ bef,
    const float* __restrict__ muf, const float* __restrict__ vaf,
    const float* __restrict__ ws, float* __restrict__ out) {
    const int g  = blockIdx.x * 256 + threadIdx.x;  // 0 .. 8388607
    const int w4 = g & 63;
    const int h  = (g >> 6) & 255;
    const int bc = g >> 14;
    const int c  = bc & 63;

    const float fh = ws[16384 + bc * 16 + (h >> 4)];
    const float fv = ws[24576 + bc * 16 + (w4 >> 2)];
    const float inv = gf[c] * rsqrtf(vaf[c] + EPS_);
    const float a   = (fh + fv) * inv + bef[c] - muf[c] * inv;
    const float sig = 1.f / (1.f + __expf(-a));

    float4 xv = ((const float4*)x)[g];
    float4 r;
    r.x = xv.x * sig;
    r.y = xv.y * sig;
    r.z = xv.z * sig;
    r.w = xv.w * sig;
    ((float4*)out)[g] = r;
}

extern "C" void kernel_launch(void* const* d_in, const int* in_sizes, int n_in,
                              void* d_out, int out_size, void* d_ws, size_t ws_size,
                              hipStream_t stream) {
    const float* x   = (const float*)d_in[0];
    const float* Wh  = (const float*)d_in[1];
    const float* bh  = (const float*)d_in[2];
    const float* Wv  = (const float*)d_in[3];
    const float* bv  = (const float*)d_in[4];
    const float* Wf  = (const float*)d_in[5];
    const float* bf  = (const float*)d_in[6];
    const float* gh  = (const float*)d_in[7];
    const float* beh = (const float*)d_in[8];
    const float* muh = (const float*)d_in[9];
    const float* vah = (const float*)d_in[10];
    const float* gv  = (const float*)d_in[11];
    const float* bev = (const float*)d_in[12];
    const float* muv = (const float*)d_in[13];
    const float* vav = (const float*)d_in[14];
    const float* gf  = (const float*)d_in[15];
    const float* bef = (const float*)d_in[16];
    const float* muf = (const float*)d_in[17];
    const float* vaf = (const float*)d_in[18];

    float* ws  = (float*)d_ws;
    float* out = (float*)d_out;

    k_pool<<<dim3(B_ * C_), dim3(256), 0, stream>>>(x, ws);
    k_mix<<<dim3(16), dim3(256), 0, stream>>>(Wh, bh, Wv, bv, Wf, bf,
                                              gh, beh, muh, vah,
                                              gv, bev, muv, vav, ws);
    k_out<<<dim3((B_ * C_ * H_ * W_) / 4 / 256), dim3(256), 0, stream>>>(
        x, gf, bef, muf, vaf, ws, out);
}

// Round 3
// 294.674 us; speedup vs baseline: 1.0100x; 1.0100x over previous
//
#include <hip/hip_runtime.h>

// StripPooling (fp32): x (8,64,256,256); PS=16.
// ws layout (floats):
//   hp  @ 0      (8192)   : (bc,16) final h-pool means
//   vpp @ 8192   (32768)  : (bc, q, 16) per-quarter vp partial sums (unnormalized)
//   fh  @ 40960  (8192)   : (bc,16)
//   fv  @ 49152  (8192)   : (bc,16)

#define B_ 8
#define C_ 64
#define H_ 256
#define W_ 256
#define EPS_ 1e-5f

// ---------------- Kernel 1: strip pooling ----------------
// grid 2048 (4 blocks per (b,c) plane, 64 rows each), block 256.
// thread t: tw = t&63 -> w chunk [4*tw,4*tw+4); th = t>>6 (== wave) -> row offset.
__global__ void __launch_bounds__(256) k_pool(const float* __restrict__ x,
                                              float* __restrict__ ws) {
    const int bid = blockIdx.x;
    const int bc  = bid >> 2;
    const int q   = bid & 3;               // row quarter: rows [q*64, q*64+64)
    const int t   = threadIdx.x;
    const int tw  = t & 63;
    const int th  = t >> 6;                // 0..3, equals wave index
    const float4* xv = (const float4*)(x + (size_t)bc * (H_ * W_) + (size_t)q * 64 * W_);

    float hbin[4] = {0.f, 0.f, 0.f, 0.f};
    float colsum = 0.f;

#pragma unroll
    for (int hi = 0; hi < 16; ++hi) {
        const int r = hi * 4 + th;         // local row 0..63
        float4 v = xv[r * 64 + tw];        // coalesced 1KB/wave
        float s = v.x + v.y + v.z + v.w;
        hbin[hi >> 2] += s;                // local h-bin = r>>4 = hi>>2 (th<4)
        colsum += s;
    }

    __shared__ float hpr[4][4];
    __shared__ float vpr[4][16];
    const int lane = t & 63;

#pragma unroll
    for (int p = 0; p < 4; ++p) {
        float v = hbin[p];
        for (int off = 32; off; off >>= 1) v += __shfl_down(v, off);
        if (lane == 0) hpr[th][p] = v;
    }
    // w-bin = tw>>2 : groups of 4 lanes share one bin
    float vsum = colsum + __shfl_down(colsum, 2, 4);
    vsum += __shfl_down(vsum, 1, 4);
    if ((lane & 3) == 0) vpr[th][lane >> 2] = vsum;
    __syncthreads();

    if (t < 4) {
        float hv = hpr[0][t] + hpr[1][t] + hpr[2][t] + hpr[3][t];
        ws[bc * 16 + q * 4 + t] = hv * (1.f / 4096.f);   // final h-pool mean
    }
    if (t < 16) {
        float vv = vpr[0][t] + vpr[1][t] + vpr[2][t] + vpr[3][t];
        ws[8192 + bc * 64 + q * 16 + t] = vv;            // partial (64-row) col sum
    }
}

// ---------------- Kernel 2: conv+BN chains on pooled strips ----------------
// grid 16: blockIdx>>3 = path (0:h,1:v), blockIdx&7 = b. block 256.
__global__ void __launch_bounds__(256) k_mix(
    const float* __restrict__ Wh, const float* __restrict__ bh,
    const float* __restrict__ Wv, const float* __restrict__ bv,
    const float* __restrict__ Wf, const float* __restrict__ bfv,
    const float* __restrict__ gh, const float* __restrict__ beh,
    const float* __restrict__ muh, const float* __restrict__ vah,
    const float* __restrict__ gv, const float* __restrict__ bev,
    const float* __restrict__ muv, const float* __restrict__ vav,
    float* __restrict__ ws) {
    const int path = blockIdx.x >> 3;
    const int b    = blockIdx.x & 7;
    float* Z       = ws + 40960 + path * 8192 + b * 1024;  // fh / fv out
    const float* W1 = path ? Wv : Wh;
    const float* b1 = path ? bv : bh;
    const float* gg = path ? gv : gh;
    const float* bb = path ? bev : beh;
    const float* mm = path ? muv : muh;
    const float* vv = path ? vav : vah;

    __shared__ float Pl[1024];
    __shared__ float Yl[1024];
    __shared__ float W1l[4096];
    __shared__ float W2l[4096];
    const int t = threadIdx.x;
    for (int i = t; i < 1024; i += 256) {
        if (path == 0) {
            Pl[i] = ws[b * 1024 + i];                      // hp, already mean
        } else {
            const int c = i >> 4, p = i & 15;
            const float* vb = ws + 8192 + (size_t)(b * 64 + c) * 64 + p;
            Pl[i] = (vb[0] + vb[16] + vb[32] + vb[48]) * (1.f / 4096.f);
        }
    }
    for (int i = t; i < 4096; i += 256) {
        W1l[i] = W1[i];
        const int o = i >> 6, c = i & 63;
        W2l[i] = Wf[o * 128 + path * 64 + c];   // Wf[:, :C] or Wf[:, C:]
    }
    __syncthreads();

    // Stage A: Y = BN(W1 @ P + b1)   (Y stored [c][p])
#pragma unroll
    for (int r = 0; r < 4; ++r) {
        const int j = t + 256 * r;
        const int c = j >> 4, p = j & 15;
        float acc = 0.f;
#pragma unroll
        for (int k = 0; k < 64; ++k) acc += W1l[c * 64 + k] * Pl[k * 16 + p];
        const float inv = gg[c] * rsqrtf(vv[c] + EPS_);
        Yl[j] = inv * (acc + b1[c]) + bb[c] - mm[c] * inv;
    }
    __syncthreads();

    // Stage B: Z = Wf_half @ Y (+ bf on the v path only)
#pragma unroll
    for (int r = 0; r < 4; ++r) {
        const int j = t + 256 * r;
        const int o = j >> 4, p = j & 15;
        float acc = path ? bfv[o] : 0.f;
#pragma unroll
        for (int k = 0; k < 64; ++k) acc += W2l[o * 64 + k] * Yl[k * 16 + p];
        Z[j] = acc;
    }
}

// ---------------- Kernel 3: epilogue ----------------
// out = sigmoid(BN_f(fh + fv)) * x. One thread per 4-elt w-chunk (4-aligned
// chunks never cross a 16-wide w-bin). bc is blockIdx-uniform -> scalar
// param loads. grid 32768, block 256.
__global__ void __launch_bounds__(256) k_out(
    const float* __restrict__ x,
    const float* __restrict__ gf, const float* __restrict__ bef,
    const float* __restrict__ muf, const float* __restrict__ vaf,
    const float* __restrict__ ws, float* __restrict__ out) {
    const int bc = blockIdx.x >> 6;                 // 64 blocks per (b,c) plane
    const int c  = bc & 63;
    const int g  = blockIdx.x * 256 + threadIdx.x;  // 0 .. 8388607
    const int w4 = g & 63;
    const int h  = (g >> 6) & 255;

    const float inv  = gf[c] * rsqrtf(vaf[c] + EPS_);     // scalar (uniform)
    const float bias = bef[c] - muf[c] * inv;

    const float fh = ws[40960 + bc * 16 + (h >> 4)];
    const float fv = ws[49152 + bc * 16 + (w4 >> 2)];
    const float a   = (fh + fv) * inv + bias;
    const float sig = 1.f / (1.f + __expf(-a));

    float4 xv = ((const float4*)x)[g];
    float4 r;
    r.x = xv.x * sig;
    r.y = xv.y * sig;
    r.z = xv.z * sig;
    r.w = xv.w * sig;
    ((float4*)out)[g] = r;
}

extern "C" void kernel_launch(void* const* d_in, const int* in_sizes, int n_in,
                              void* d_out, int out_size, void* d_ws, size_t ws_size,
                              hipStream_t stream) {
    const float* x   = (const float*)d_in[0];
    const float* Wh  = (const float*)d_in[1];
    const float* bh  = (const float*)d_in[2];
    const float* Wv  = (const float*)d_in[3];
    const float* bv  = (const float*)d_in[4];
    const float* Wf  = (const float*)d_in[5];
    const float* bf  = (const float*)d_in[6];
    const float* gh  = (const float*)d_in[7];
    const float* beh = (const float*)d_in[8];
    const float* muh = (const float*)d_in[9];
    const float* vah = (const float*)d_in[10];
    const float* gv  = (const float*)d_in[11];
    const float* bev = (const float*)d_in[12];
    const float* muv = (const float*)d_in[13];
    const float* vav = (const float*)d_in[14];
    const float* gf  = (const float*)d_in[15];
    const float* bef = (const float*)d_in[16];
    const float* muf = (const float*)d_in[17];
    const float* vaf = (const float*)d_in[18];

    float* ws  = (float*)d_ws;
    float* out = (float*)d_out;

    k_pool<<<dim3(B_ * C_ * 4), dim3(256), 0, stream>>>(x, ws);
    k_mix<<<dim3(16), dim3(256), 0, stream>>>(Wh, bh, Wv, bv, Wf, bf,
                                              gh, beh, muh, vah,
                                              gv, bev, muv, vav, ws);
    k_out<<<dim3((B_ * C_ * H_ * W_) / 4 / 256), dim3(256), 0, stream>>>(
        x, gf, bef, muf, vaf, ws, out);
}